// Round 1
// baseline (356.051 us; speedup 1.0000x reference)
//
#include <hip/hip_runtime.h>

// NeuralFM forward, MI355X (gfx950).
// B=16384, F=50, D=64, L1=128, L2=64.
// R3: one wave per block (4096 blocks x 64 thr) -- all LDS is wave-private, so
// single-wave workgroups make every __syncthreads() free and remove the
// multi-wave vmcnt(0)+barrier convoy during the random gather.
// 32-bit voffset gather addressing; float2 W1 loads (2 outputs/lane).

#define NFIELDS 50
#define HIDDEN  64
#define L1N     128
#define L2N     64
#define RPW     4                  // rows per block (one wave)

__global__ __launch_bounds__(64, 4) void neuralfm_kernel(
    const int*   __restrict__ features,   // [B, 50]
    const float* __restrict__ emb,        // [1e6, 64]
    const float* __restrict__ bias_t,     // [1e6]
    const float* __restrict__ w_bias,     // [1]
    const float* __restrict__ W1,         // [64, 128]
    const float* __restrict__ b1,         // [128]
    const float* __restrict__ W2,         // [128, 64]
    const float* __restrict__ b2,         // [64]
    const float* __restrict__ Wp,         // [64]
    const float* __restrict__ bp,         // [1]
    float*       __restrict__ out)        // [B]
{
    __shared__ int    sIdx[RPW * NFIELDS];        // 800 B
    __shared__ float4 sFm4[RPW * HIDDEN / 4];     // 1 KB
    __shared__ float  sH1 [RPW * L1N];            // 2 KB

    const int lane = threadIdx.x;      // 0..63 (one wave)
    const int sub  = lane >> 4;        // which of 4 rows this lane serves
    const int le   = lane & 15;        // dim-quad within the row
    const int row0 = blockIdx.x * RPW;

    // ---- phase 0: coalesced index load (200 contiguous ints) ----
    const int idx_base = row0 * NFIELDS;
    #pragma unroll
    for (int t = lane; t < RPW * NFIELDS; t += 64)
        sIdx[t] = features[idx_base + t];
    __syncthreads();                   // single wave: free

    // ---- early first-order bias gather: latency hides under gather+MLP ----
    float biasacc[RPW];
    #pragma unroll
    for (int r = 0; r < RPW; ++r) biasacc[r] = 0.f;
    if (lane < NFIELDS) {
        #pragma unroll
        for (int r = 0; r < RPW; ++r)
            biasacc[r] = bias_t[sIdx[r * NFIELDS + lane]];
    }

    // ---- phase 1: float4 embedding gather + FM pooling ----
    // byte offset = idx*256 + le*16  (max 2.56e8, fits u32 -> sgpr-base+voffset)
    const char* __restrict__ embB = (const char*)emb;
    const unsigned leoff = (unsigned)(le * 16);
    float sx = 0.f, sy = 0.f, sz = 0.f, sw = 0.f;   // sum
    float qx = 0.f, qy = 0.f, qz = 0.f, qw = 0.f;   // sum of squares
    const int* myIdx = &sIdx[sub * NFIELDS];
    #pragma unroll
    for (int f = 0; f < NFIELDS; ++f) {
        const unsigned off = (unsigned)myIdx[f] * 256u + leoff;  // LDS broadcast
        const float4 v = *(const float4*)(embB + off);
        sx += v.x; sy += v.y; sz += v.z; sw += v.w;
        qx += v.x * v.x; qy += v.y * v.y; qz += v.z * v.z; qw += v.w * v.w;
    }
    float4 fm;
    fm.x = 0.5f * (sx * sx - qx);
    fm.y = 0.5f * (sy * sy - qy);
    fm.z = 0.5f * (sz * sz - qz);
    fm.w = 0.5f * (sw * sw - qw);
    sFm4[sub * (HIDDEN / 4) + le] = fm;
    __syncthreads();                   // single wave: free

    // ---- phase 2: h1 = relu(fm @ W1 + b1); lane owns outputs {2l, 2l+1} ----
    float h1x[RPW], h1y[RPW];
    #pragma unroll
    for (int r = 0; r < RPW; ++r) { h1x[r] = 0.f; h1y[r] = 0.f; }
    const int n0 = 2 * lane;

    for (int dq = 0; dq < HIDDEN / 4; ++dq) {
        float2 w[4];
        #pragma unroll
        for (int c = 0; c < 4; ++c)
            w[c] = *(const float2*)&W1[(4 * dq + c) * L1N + n0];   // 8B coalesced
        #pragma unroll
        for (int r = 0; r < RPW; ++r) {
            const float4 fv = sFm4[r * (HIDDEN / 4) + dq];         // b128 broadcast
            h1x[r] += fv.x * w[0].x + fv.y * w[1].x + fv.z * w[2].x + fv.w * w[3].x;
            h1y[r] += fv.x * w[0].y + fv.y * w[1].y + fv.z * w[2].y + fv.w * w[3].y;
        }
    }
    const float2 b1v = *(const float2*)&b1[n0];
    #pragma unroll
    for (int r = 0; r < RPW; ++r) {
        float2 hv;
        hv.x = fmaxf(h1x[r] + b1v.x, 0.f);
        hv.y = fmaxf(h1y[r] + b1v.y, 0.f);
        *(float2*)&sH1[r * L1N + n0] = hv;
    }
    __syncthreads();                   // single wave: free

    // ---- phase 3: h2 = relu(h1 @ W2 + b2); lane owns output `lane` ----
    const float4* sH14 = (const float4*)sH1;
    float h2[RPW];
    #pragma unroll
    for (int r = 0; r < RPW; ++r) h2[r] = 0.f;

    for (int jq = 0; jq < L1N / 4; ++jq) {
        float w[4];
        #pragma unroll
        for (int c = 0; c < 4; ++c)
            w[c] = W2[(4 * jq + c) * L2N + lane];           // coalesced, L2-hot
        #pragma unroll
        for (int r = 0; r < RPW; ++r) {
            const float4 hv = sH14[r * (L1N / 4) + jq];     // b128 broadcast
            h2[r] += hv.x * w[0] + hv.y * w[1] + hv.z * w[2] + hv.w * w[3];
        }
    }
    const float bias2 = b2[lane];
    const float wp    = Wp[lane];

    float tot[RPW];
    #pragma unroll
    for (int r = 0; r < RPW; ++r)
        tot[r] = fmaxf(h2[r] + bias2, 0.f) * wp + biasacc[r];

    // ---- phase 4: wave reduce (pred + feature_bias), add global terms, store ----
    #pragma unroll
    for (int r = 0; r < RPW; ++r) {
        float v = tot[r];
        #pragma unroll
        for (int off = 32; off > 0; off >>= 1)
            v += __shfl_xor(v, off, 64);
        tot[r] = v;
    }
    if (lane < RPW) {
        float v = tot[0];
        v = (lane == 1) ? tot[1] : v;
        v = (lane == 2) ? tot[2] : v;
        v = (lane == 3) ? tot[3] : v;
        out[row0 + lane] = v + bp[0] + w_bias[0];   // 4-lane coalesced store
    }
}

extern "C" void kernel_launch(void* const* d_in, const int* in_sizes, int n_in,
                              void* d_out, int out_size, void* d_ws, size_t ws_size,
                              hipStream_t stream) {
    const int*   features = (const int*)  d_in[0];
    // d_in[1] = labels (values unused by the forward pass)
    const float* emb      = (const float*)d_in[2];
    const float* bias_t   = (const float*)d_in[3];
    const float* w_bias   = (const float*)d_in[4];
    const float* W1       = (const float*)d_in[5];
    const float* b1       = (const float*)d_in[6];
    const float* W2       = (const float*)d_in[7];
    const float* b2       = (const float*)d_in[8];
    const float* Wp       = (const float*)d_in[9];
    const float* bp       = (const float*)d_in[10];
    float*       out      = (float*)d_out;

    const int batch  = in_sizes[0] / NFIELDS;        // 16384
    const int blocks = batch / RPW;                  // 4096

    neuralfm_kernel<<<blocks, 64, 0, stream>>>(
        features, emb, bias_t, w_bias, W1, b1, W2, b2, Wp, bp, out);
}